// Round 20
// baseline (549.272 us; speedup 1.0000x reference)
//
#include <hip/hip_runtime.h>
#include <math.h>

#define DEV __device__ __forceinline__

typedef float f32x4 __attribute__((ext_vector_type(4)));
typedef __bf16 bf16x8 __attribute__((ext_vector_type(8)));

DEV unsigned short f2bf(float f){
  unsigned int u = __float_as_uint(f);
  u = (u + 0x7FFFu + ((u >> 16) & 1u)) >> 16;   // RNE
  return (unsigned short)u;
}
DEV float bf2f(unsigned short s){
  return __uint_as_float(((unsigned int)s) << 16);
}

DEV float wredf(float v){
  v += __shfl_xor(v, 32, 64);
  v += __shfl_xor(v, 16, 64);
  v += __shfl_xor(v, 8, 64);
  v += __shfl_xor(v, 4, 64);
  v += __shfl_xor(v, 2, 64);
  v += __shfl_xor(v, 1, 64);
  return v;
}

// ---------------- h0: (B,3,256,256) -> (B,256,256,4) bf16 with time ---------
__global__ void h0_kernel(const float* __restrict__ x, unsigned short* __restrict__ h0){
  int idx = blockIdx.x*256 + threadIdx.x;            // < 32*65536
  int b = idx >> 16, p = idx & 65535;
  const float* xb = x + (size_t)b*3*65536;
  float v0 = xb[p], v1 = xb[65536 + p], v2 = xb[131072 + p];
  float t = sqrtf(v0*v0 + v1*v1 + v2*v2 + 1.f);
  ushort4 o;
  o.x = f2bf(t); o.y = f2bf(v0); o.z = f2bf(v1); o.w = f2bf(v2);
  *(ushort4*)&h0[(size_t)idx*4] = o;
}

// ---------------- fused setup: conv-W repacks + wtail + zero mvacc/red ------
__global__ void setup_kernel(const float* __restrict__ cw0, const float* __restrict__ cw1,
                             const float* __restrict__ cw2, const float* __restrict__ cw3,
                             const float* __restrict__ wm, const float* __restrict__ wv,
                             unsigned short* __restrict__ cwb0, unsigned short* __restrict__ cwb1,
                             unsigned short* __restrict__ cwb2, unsigned short* __restrict__ cwb3,
                             float* __restrict__ wtail, float* __restrict__ mvacc,
                             float* __restrict__ red){
  int idx = blockIdx.x*256 + threadIdx.x;
  if (idx < 1024){
    int n = idx >> 5, kk = idx & 31;
    unsigned short v = 0;
    if (kk < 27){ int kp = kk/3, c = kk - kp*3; v = f2bf(cw0[(size_t)(n+1)*28 + 1 + c*9 + kp]); }
    cwb0[idx] = v;
    return;
  }
  idx -= 1024;
  if (idx < 18432){
    int n = idx / 288, kk = idx - n*288;
    int kp = kk / 32, c = kk - kp*32;
    cwb1[idx] = f2bf(cw1[(size_t)(n+1)*289 + 1 + c*9 + kp]);
    return;
  }
  idx -= 18432;
  if (idx < 73728){
    int n = idx / 576, kk = idx - n*576;
    int kp = kk / 64, c = kk - kp*64;
    cwb2[idx] = f2bf(cw2[(size_t)(n+1)*577 + 1 + c*9 + kp]);
    return;
  }
  idx -= 73728;
  if (idx < 294912){
    int n = idx / 1152, kk = idx - n*1152;
    int kp = kk / 128, c = kk - kp*128;
    cwb3[idx] = f2bf(cw3[(size_t)(n+1)*1153 + 1 + c*9 + kp]);
    return;
  }
  idx -= 294912;
  if (idx < 1024){
    wtail[idx] = (idx < 512) ? wm[(size_t)(idx + 1)*65537 + 65536]
                             : wv[(size_t)(idx - 511)*65537 + 65536];
    return;
  }
  idx -= 1024;
  if (idx < 32768){ mvacc[idx] = 0.f; return; }
  idx -= 32768;
  if (idx < 8224) red[idx] = 0.f;
}

// ---------------- conv layer 0 + fused time & channel sums (bf16 Y) --------
__global__ __launch_bounds__(256) void conv0_mfma_kernel(
    const unsigned short* __restrict__ h0bf, const unsigned short* __restrict__ wrp0,
    const float* __restrict__ Wm, const float* __restrict__ bias,
    unsigned short* __restrict__ y, float* __restrict__ red){
  __shared__ __align__(16) unsigned short A_lds[64][40];
  __shared__ __align__(16) unsigned short B_lds[32][40];
  __shared__ float Tsq[64][9];
  __shared__ float tA[64];
  __shared__ float bins[33];
  int tid = threadIdx.x;
  int tile = blockIdx.x, b = blockIdx.y;
  int oy0 = (tile >> 4) * 8, ox0 = (tile & 15) * 8;
  for (int i = tid; i < 320; i += 256){
    uint4 z = {0,0,0,0};
    *(uint4*)&A_lds[i/5][(i%5)*8] = z;
  }
  if (tid < 128)
    *(uint4*)&B_lds[tid>>2][(tid&3)*8] = *(const uint4*)&wrp0[(size_t)(tid>>2)*32 + (tid&3)*8];
  if (tid < 33) bins[tid] = 0.f;
  __syncthreads();
  for (int i = tid; i < 576; i += 256){
    int m = i/9, kp = i - (i/9)*9;
    int py = oy0 + (m >> 3), px = ox0 + (m & 7);
    int iy = py*2 + kp/3 - 1, ix = px*2 + kp%3 - 1;
    ushort4 v = {0x3F80, 0, 0, 0};     // OOB: t clamps to 1, space 0
    if ((unsigned)iy < 256u && (unsigned)ix < 256u)
      v = *(const ushort4*)&h0bf[((size_t)(b*256 + iy)*256 + ix)*4];
    A_lds[m][kp*3 + 0] = v.y;
    A_lds[m][kp*3 + 1] = v.z;
    A_lds[m][kp*3 + 2] = v.w;
    float tv = fmaxf(bf2f(v.x), 1.f);
    Tsq[m][kp] = tv*tv;
  }
  __syncthreads();
  if (tid < 64){
    float s = 0.f;
    #pragma unroll
    for (int kp = 0; kp < 9; ++kp) s += Tsq[tid][kp];
    tA[tid] = sqrtf(fmaxf(s - 8.f, 0.f));
  }
  int wave = tid >> 6, lane = tid & 63;
  int row = lane & 15, kb = lane >> 4;
  int m0 = wave * 16;
  f32x4 zero = {0.f,0.f,0.f,0.f};
  f32x4 acc0 = zero, acc1 = zero;
  bf16x8 af = *(const bf16x8*)&A_lds[m0 + row][kb*8];
  bf16x8 b0 = *(const bf16x8*)&B_lds[row][kb*8];
  bf16x8 b1 = *(const bf16x8*)&B_lds[16 + row][kb*8];
  acc0 = __builtin_amdgcn_mfma_f32_16x16x32_bf16(af, b0, acc0, 0, 0, 0);
  acc1 = __builtin_amdgcn_mfma_f32_16x16x32_bf16(af, b1, acc1, 0, 0, 0);
  __syncthreads();   // tA ready
  int o0 = row + 1, o1 = 17 + row;
  float bv0 = bias[o0], w00 = Wm[(size_t)o0*28];
  float bv1 = bias[o1], w01 = Wm[(size_t)o1*28];
  float v0[4], v1[4];
  #pragma unroll
  for (int r = 0; r < 4; ++r){
    int m = m0 + kb*4 + r;
    v0[r] = acc0[r] + bv0 + tA[m]*w00;
    v1[r] = acc1[r] + bv1 + tA[m]*w01;
    int py = oy0 + (m >> 3), px = ox0 + (m & 7);
    size_t pb_ = ((size_t)(b*128 + py)*128 + px)*33;
    y[pb_ + o0] = f2bf(v0[r]);
    y[pb_ + o1] = f2bf(v1[r]);
  }
  float sq[4];
  #pragma unroll
  for (int r = 0; r < 4; ++r) sq[r] = v0[r]*v0[r] + v1[r]*v1[r];
  #pragma unroll
  for (int msk = 1; msk <= 8; msk <<= 1)
    #pragma unroll
    for (int r = 0; r < 4; ++r) sq[r] += __shfl_xor(sq[r], msk, 64);
  float tvs = 0.f;
  #pragma unroll
  for (int r = 0; r < 4; ++r){
    float tv = sqrtf(sq[r] + 1.f);
    tvs += tv;
    if (row == 0){
      int m = m0 + kb*4 + r;
      int py = oy0 + (m >> 3), px = ox0 + (m & 7);
      y[((size_t)(b*128 + py)*128 + px)*33] = f2bf(tv);
    }
  }
  float cs0 = v0[0] + v0[1] + v0[2] + v0[3];
  float cs1 = v1[0] + v1[1] + v1[2] + v1[3];
  cs0 += __shfl_xor(cs0, 16, 64); cs0 += __shfl_xor(cs0, 32, 64);
  cs1 += __shfl_xor(cs1, 16, 64); cs1 += __shfl_xor(cs1, 32, 64);
  tvs += __shfl_xor(tvs, 16, 64); tvs += __shfl_xor(tvs, 32, 64);
  if (kb == 0){
    atomicAdd(&bins[o0], cs0);
    atomicAdd(&bins[o1], cs1);
    if (row == 0) atomicAdd(&bins[0], tvs);
  }
  __syncthreads();
  if (tid < 33) atomicAdd(&red[(size_t)b*33 + tid], bins[tid]);
}

// ---------------- conv layers 1-3: split Sp/T, repacked W, optional fusion --
template<int CS, int COUT, int KPC, int NSPLIT, bool FUSE, bool YBF>
__global__ __launch_bounds__(256) void conv2_mfma_kernel(
    const unsigned short* __restrict__ sp_in, const unsigned short* __restrict__ t_in,
    const unsigned short* __restrict__ wrp, const float* __restrict__ Wm,
    const float* __restrict__ bias, void* __restrict__ yv_,
    float* __restrict__ red, int Hin, int Ho){
  constexpr int KROW = 9*CS;
  __shared__ __align__(16) unsigned short A_lds[64][40];
  __shared__ __align__(16) unsigned short B_lds[64][40];
  __shared__ float tA[64];
  __shared__ float ssqS[FUSE ? 64 : 1];
  __shared__ float binsS[FUSE ? COUT : 1];
  float* yf = (float*)yv_;
  unsigned short* yh = (unsigned short*)yv_;
  int tid = threadIdx.x;
  int wave = tid >> 6, lane = tid & 63;
  int tilesX = Ho >> 3;
  int tile = blockIdx.x, b = blockIdx.y;
  int zt = blockIdx.z / NSPLIT, sp = blockIdx.z % NSPLIT;
  int zbase = zt * 64;
  int oy0 = (tile / tilesX) * 8, ox0 = (tile % tilesX) * 8;
  int m0 = (wave >> 1) * 32, n0 = (wave & 1) * 32;
  int row = lane & 15, kb = lane >> 4;
  if (FUSE){
    if (tid < 64) ssqS[tid] = 0.f;
    for (int i = tid; i < COUT; i += 256) binsS[i] = 0.f;
  }
  if (sp == 0 && tid < 64){
    int m = tid;
    int py = oy0 + (m >> 3), px = ox0 + (m & 7);
    float s = 0.f;
    #pragma unroll
    for (int kp = 0; kp < 9; ++kp){
      int iy = py*2 + kp/3 - 1, ix = px*2 + kp%3 - 1;
      float tv = 1.f;
      if ((unsigned)iy < (unsigned)Hin && (unsigned)ix < (unsigned)Hin)
        tv = fmaxf(bf2f(t_in[(size_t)(b*Hin + iy)*Hin + ix]), 1.f);
      s = fmaf(tv, tv, s);
    }
    tA[m] = sqrtf(fmaxf(s - 8.f, 0.f));
  }
  f32x4 zero = {0.f,0.f,0.f,0.f};
  f32x4 acc[2][2] = {{zero,zero},{zero,zero}};
  int ar = tid >> 2, aseg = tid & 3;
  int apy = oy0 + (ar >> 3), apx = ox0 + (ar & 7);
  for (int ch = sp*KPC; ch < sp*KPC + KPC; ++ch){
    int kglob = ch * 32;
    int kp = kglob / CS, c0 = kglob % CS;
    int iy = apy*2 + kp/3 - 1, ix = apx*2 + kp%3 - 1;
    uint4 va = {0,0,0,0};
    if ((unsigned)iy < (unsigned)Hin && (unsigned)ix < (unsigned)Hin)
      va = *(const uint4*)&sp_in[((size_t)(b*Hin + iy)*Hin + ix)*CS + c0 + aseg*8];
    uint4 vb = *(const uint4*)&wrp[(size_t)(zbase + ar)*KROW + kglob + aseg*8];
    __syncthreads();                       // prev chunk reads done
    *(uint4*)&A_lds[ar][aseg*8] = va;
    *(uint4*)&B_lds[ar][aseg*8] = vb;
    __syncthreads();
    bf16x8 af0 = *(const bf16x8*)&A_lds[m0 + row][kb*8];
    bf16x8 af1 = *(const bf16x8*)&A_lds[m0 + 16 + row][kb*8];
    bf16x8 bf0 = *(const bf16x8*)&B_lds[n0 + row][kb*8];
    bf16x8 bf1 = *(const bf16x8*)&B_lds[n0 + 16 + row][kb*8];
    acc[0][0] = __builtin_amdgcn_mfma_f32_16x16x32_bf16(af0, bf0, acc[0][0], 0, 0, 0);
    acc[0][1] = __builtin_amdgcn_mfma_f32_16x16x32_bf16(af0, bf1, acc[0][1], 0, 0, 0);
    acc[1][0] = __builtin_amdgcn_mfma_f32_16x16x32_bf16(af1, bf0, acc[1][0], 0, 0, 0);
    acc[1][1] = __builtin_amdgcn_mfma_f32_16x16x32_bf16(af1, bf1, acc[1][1], 0, 0, 0);
  }
  __syncthreads();
  float vv[2][2][4];
  #pragma unroll
  for (int mi = 0; mi < 2; ++mi)
    #pragma unroll
    for (int ni = 0; ni < 2; ++ni){
      int col = n0 + 16*ni + row;
      int o = zbase + 1 + col;
      float bv = 0.f, w0 = 0.f;
      if (sp == 0){ bv = bias[o]; w0 = Wm[(size_t)o*(KROW + 1)]; }
      #pragma unroll
      for (int r = 0; r < 4; ++r){
        int m = m0 + 16*mi + kb*4 + r;
        int py = oy0 + (m >> 3), px = ox0 + (m & 7);
        size_t idx = ((size_t)(b*Ho + py)*Ho + px)*COUT + o;
        float val = acc[mi][ni][r];
        if (sp == 0) val += bv + tA[m]*w0;
        vv[mi][ni][r] = val;
        if (YBF)              yh[idx] = f2bf(val);
        else if (NSPLIT > 1)  atomicAdd(&yf[idx], val);
        else                  yf[idx] = val;
      }
    }
  if (FUSE){
    float sq[2][4];
    #pragma unroll
    for (int mi = 0; mi < 2; ++mi)
      #pragma unroll
      for (int r = 0; r < 4; ++r)
        sq[mi][r] = vv[mi][0][r]*vv[mi][0][r] + vv[mi][1][r]*vv[mi][1][r];
    #pragma unroll
    for (int msk = 1; msk <= 8; msk <<= 1)
      #pragma unroll
      for (int mi = 0; mi < 2; ++mi)
        #pragma unroll
        for (int r = 0; r < 4; ++r) sq[mi][r] += __shfl_xor(sq[mi][r], msk, 64);
    if (row == 0){
      #pragma unroll
      for (int mi = 0; mi < 2; ++mi)
        #pragma unroll
        for (int r = 0; r < 4; ++r)
          atomicAdd(&ssqS[m0 + 16*mi + kb*4 + r], sq[mi][r]);
    }
    float cs[2];
    #pragma unroll
    for (int ni = 0; ni < 2; ++ni){
      cs[ni] = 0.f;
      #pragma unroll
      for (int mi = 0; mi < 2; ++mi)
        #pragma unroll
        for (int r = 0; r < 4; ++r) cs[ni] += vv[mi][ni][r];
      cs[ni] += __shfl_xor(cs[ni], 16, 64);
      cs[ni] += __shfl_xor(cs[ni], 32, 64);
    }
    if (kb == 0){
      atomicAdd(&binsS[1 + n0 + row], cs[0]);
      atomicAdd(&binsS[1 + n0 + 16 + row], cs[1]);
    }
    __syncthreads();
    if (tid < 64){
      float tv = sqrtf(ssqS[tid] + 1.f);
      int py = oy0 + (tid >> 3), px = ox0 + (tid & 7);
      size_t idx = ((size_t)(b*Ho + py)*Ho + px)*COUT;
      if (YBF) yh[idx] = f2bf(tv);
      else     yf[idx] = tv;
      atomicAdd(&binsS[0], tv);
    }
    __syncthreads();
    for (int i = tid; i < COUT; i += 256)
      atomicAdd(&red[(size_t)b*COUT + i], binsS[i]);
  }
}

// ---------------- time channel via LDS tile (L2/L3 only, fp32) --------------
template<int C, int TP>
__global__ __launch_bounds__(256) void time_tile_kernel(float* __restrict__ y){
  constexpr int TPR = 256 / TP;
  __shared__ float tile[TP*C];
  int tid = threadIdx.x;
  size_t base = (size_t)blockIdx.x * TP * C;
  for (int i = tid; i < TP*C; i += 256) tile[i] = y[base + i];
  __syncthreads();
  int r = tid / TPR, seg = tid % TPR;
  float ss = 0.f;
  for (int c = 1 + seg; c < C; c += TPR){ float v = tile[r*C + c]; ss = fmaf(v, v, ss); }
  #pragma unroll
  for (int m = TPR/2; m >= 1; m >>= 1) ss += __shfl_xor(ss, m, 64);
  if (seg == 0) y[base + (size_t)r*C] = sqrtf(ss + 1.f);
}

// ---------------- coalesced channel sums (L2/L3 only, fp32) -----------------
template<int C>
__global__ __launch_bounds__(256) void rsum_coal_kernel(const float* __restrict__ y,
    float* __restrict__ red, int N, int BPB){
  constexpr int S = (4096 / C) * C;
  __shared__ float bins[C];
  int tid = threadIdx.x;
  for (int i = tid; i < C; i += 256) bins[i] = 0.f;
  int b = blockIdx.y, blk = blockIdx.x;
  size_t per = (size_t)(N / BPB) * C;
  const float* yb = y + (size_t)b*N*C + (size_t)blk*per;
  float a[16];
  #pragma unroll
  for (int k = 0; k < 16; ++k) a[k] = 0.f;
  for (size_t off = 0; off < per; off += S){
    #pragma unroll
    for (int k = 0; k < 16; ++k){
      int e = k*256 + tid;
      if (e < S && off + e < per) a[k] += yb[off + e];
    }
  }
  __syncthreads();            // bins zeroed
  #pragma unroll
  for (int k = 0; k < 16; ++k){
    int e = k*256 + tid;
    if (e < S) atomicAdd(&bins[e % C], a[k]);
  }
  __syncthreads();
  for (int i = tid; i < C; i += 256) atomicAdd(&red[(size_t)b*C + i], bins[i]);
}

// ---------------- fused stats: per-b centroid + centroid-of-centroids -------
__global__ __launch_bounds__(256) void stats_kernel(float* __restrict__ red,
    float* __restrict__ mean, float* __restrict__ scal, int N, int C){
  __shared__ float cent[8224];      // 32 x C (C<=257)
  __shared__ float s[256];
  int tid = threadIdx.x;
  int wave = tid >> 6, lane = tid & 63;
  for (int j = 0; j < 8; ++j){
    int b = wave*8 + j;
    float va[5]; float d = 0.f;
    #pragma unroll
    for (int k = 0; k < 5; ++k){
      int c = lane + 64*k;
      float v = 0.f;
      if (c < C){ v = red[(size_t)b*C + c] / (float)N; red[(size_t)b*C + c] = 0.f; }
      va[k] = v;
      float pr = v*v;
      d += (c == 0) ? -pr : pr;
    }
    float den = sqrtf(fmaxf(fabsf(wredf(d)), 1e-8f));
    #pragma unroll
    for (int k = 0; k < 5; ++k){
      int c = lane + 64*k;
      if (c < C) cent[b*C + c] = va[k] / den;
    }
  }
  __syncthreads();
  float va = 0.f, vb = 0.f;
  if (tid < C){
    #pragma unroll 4
    for (int b = 0; b < 32; ++b) va += cent[b*C + tid];
    va *= 0.03125f;
  }
  if (tid + 256 < C){
    #pragma unroll 4
    for (int b = 0; b < 32; ++b) vb += cent[b*C + tid + 256];
    vb *= 0.03125f;
  }
  float pr = ((tid == 0) ? -va*va : va*va) + vb*vb;
  s[tid] = pr; __syncthreads();
  for (int st = 128; st; st >>= 1){ if (tid < st) s[tid] += s[tid+st]; __syncthreads(); }
  float den2 = sqrtf(fmaxf(fabsf(s[0]), 1e-8f));
  if (tid < C) mean[tid] = va / den2;
  if (tid + 256 < C) mean[tid + 256] = vb / den2;
  if (tid < 40) scal[tid] = 0.f;
}

// ---------------- Frechet variance, thread-per-point (YBF: bf16 input) ------
template<int C, bool YBF>
__global__ __launch_bounds__(256) void bn_var_t_kernel(const void* __restrict__ yv_,
    const float* __restrict__ mean, float* __restrict__ scal, int P){
  __shared__ float sm[C];
  __shared__ float part[4];
  const float* yf = (const float*)yv_;
  const unsigned short* yh = (const unsigned short*)yv_;
  for (int i = threadIdx.x; i < C; i += 256) sm[i] = mean[i];
  __syncthreads();
  float acc = 0.f;
  int stride = gridDim.x * 256;
  for (int p = blockIdx.x*256 + threadIdx.x; p < P; p += stride){
    float a[C];
    float d1 = 0.f;
    #pragma unroll
    for (int c = 0; c < C; ++c){
      a[c] = YBF ? bf2f(yh[(size_t)p*C + c]) : yf[(size_t)p*C + c];
      float pr = a[c]*sm[c];
      d1 += (c == 0) ? -pr : pr;
    }
    float xy = d1;
    float dist = acoshf(fmaxf(-xy, 1.f + 1e-7f));
    float d2 = 0.f;
    #pragma unroll
    for (int c = 0; c < C; ++c){
      a[c] = fmaf(xy, sm[c], a[c]);
      float pr = a[c]*a[c];
      d2 += (c == 0) ? -pr : pr;
    }
    float den = sqrtf(fmaxf(d2, 1e-8f));
    float sc = dist / den;
    float corr = -(a[0]*sc) / (1.f + sm[0]);
    float ns = 0.f;
    #pragma unroll
    for (int c = 0; c < C; ++c){
      float uc = fmaf(corr, sm[c] + ((c == 0) ? 1.f : 0.f), a[c]*sc);
      ns = fmaf(uc, uc, ns);
    }
    acc += sqrtf(ns);
  }
  acc = wredf(acc);
  if ((threadIdx.x & 63) == 0) part[threadIdx.x >> 6] = acc;
  __syncthreads();
  if (threadIdx.x == 0)
    atomicAdd(scal, part[0] + part[1] + part[2] + part[3]);
}

// ---------------- BN apply, thread-per-point, split bf16 out (L0-2) ---------
template<int C, bool YBF>
__global__ __launch_bounds__(256) void bn_apply_sp_kernel(const void* __restrict__ yv_,
    const float* __restrict__ mean, const float* __restrict__ beta,
    const float* __restrict__ gamma, const float* __restrict__ scal,
    unsigned short* __restrict__ sp_out, unsigned short* __restrict__ t_out, int P){
  __shared__ float sm[C];
  __shared__ float sb[C];
  const float* yf = (const float*)yv_;
  const unsigned short* yh = (const unsigned short*)yv_;
  for (int i = threadIdx.x; i < C; i += 256){ sm[i] = mean[i]; sb[i] = beta[i]; }
  __syncthreads();
  int p = blockIdx.x*256 + threadIdx.x;
  if (p >= P) return;
  float a[C];
  float d1 = 0.f;
  #pragma unroll
  for (int c = 0; c < C; ++c){
    a[c] = YBF ? bf2f(yh[(size_t)p*C + c]) : yf[(size_t)p*C + c];
    float pr = a[c]*sm[c];
    d1 += (c == 0) ? -pr : pr;
  }
  float xy = d1;
  float dist = acoshf(fmaxf(-xy, 1.f + 1e-7f));
  float d2 = 0.f;
  #pragma unroll
  for (int c = 0; c < C; ++c){
    a[c] = fmaf(xy, sm[c], a[c]);
    float pr = a[c]*a[c];
    d2 += (c == 0) ? -pr : pr;
  }
  float den = sqrtf(fmaxf(d2, 1e-8f));
  float sc = dist / den;
  float corr = -(a[0]*sc) / (1.f + sm[0]);
  float var = scal[0] / (float)P;
  float g = gamma[0] / (var + 1e-5f);
  #pragma unroll
  for (int c = 0; c < C; ++c)
    a[c] = fmaf(corr, sm[c] + ((c == 0) ? 1.f : 0.f), a[c]*sc) * g;
  float d3 = 0.f;
  #pragma unroll
  for (int c = 0; c < C; ++c){
    float pr = a[c]*sb[c];
    d3 += (c == 0) ? -pr : pr;
  }
  float cb = d3 / (1.f + sb[0]);
  float d4 = 0.f;
  #pragma unroll
  for (int c = 0; c < C; ++c){
    a[c] = fmaf(cb, sb[c] + ((c == 0) ? 1.f : 0.f), a[c]);
    float pr = a[c]*a[c];
    d4 += (c == 0) ? -pr : pr;
  }
  float nu = sqrtf(fmaxf(d4, 1e-8f));
  float ch = coshf(nu), shn = sinhf(nu) / nu;
  unsigned short* hp = sp_out + (size_t)p * (C - 1);
  float ssum = 0.f;
  #pragma unroll
  for (int c = 1; c < C; ++c){
    float r = fmaxf(fmaf(ch, sb[c], shn*a[c]), 0.f);
    hp[c-1] = f2bf(r);
    ssum = fmaf(r, r, ssum);
  }
  t_out[p] = f2bf(sqrtf(ssum + 1.f));
}

// ---------------- L3 (C=257) wave-per-point fallbacks (fp32) ----------------
__global__ void bn_var_kernel(const float* __restrict__ y, const float* __restrict__ mean,
                              float* __restrict__ scal, int P, int C){
  __shared__ float smean[260];
  __shared__ float part[4];
  for (int i = threadIdx.x; i < C; i += blockDim.x) smean[i] = mean[i];
  __syncthreads();
  int wv = threadIdx.x >> 6, lane = threadIdx.x & 63;
  int nwaves = gridDim.x * 4;
  float m0 = smean[0];
  float ms[5];
  #pragma unroll
  for (int j = 0; j < 5; ++j){
    int c = lane + 64*j;
    ms[j] = (c < C) ? smean[c] : 0.f;
  }
  float vsum = 0.f;
  for (int p = blockIdx.x*4 + wv; p < P; p += nwaves){
    const float* yp = y + (size_t)p * C;
    float yvv[5], nom[5];
    #pragma unroll
    for (int j = 0; j < 5; ++j){
      int c = lane + 64*j;
      yvv[j] = (c < C) ? yp[c] : 0.f;
    }
    float d1 = 0.f;
    #pragma unroll
    for (int j = 0; j < 5; ++j){
      int c = lane + 64*j;
      float prd = yvv[j]*ms[j];
      d1 += (c == 0) ? -prd : prd;
    }
    float xy = wredf(d1);
    float dist = acoshf(fmaxf(-xy, 1.f + 1e-7f));
    float d2 = 0.f;
    #pragma unroll
    for (int j = 0; j < 5; ++j){
      int c = lane + 64*j;
      nom[j] = yvv[j] + xy*ms[j];
      float prd = nom[j]*nom[j];
      d2 += (c == 0) ? -prd : prd;
    }
    float den = sqrtf(fmaxf(wredf(d2), 1e-8f));
    float sc = dist / den;
    float u0 = __shfl(nom[0], 0, 64) * sc;
    float corr = -u0 / (1.f + m0);
    float nsum = 0.f;
    #pragma unroll
    for (int j = 0; j < 5; ++j){
      int c = lane + 64*j;
      float uc = nom[j]*sc + corr*(ms[j] + ((c == 0) ? 1.f : 0.f));
      nsum += uc*uc;
    }
    nsum = wredf(nsum);
    vsum += sqrtf(nsum);
  }
  if (lane == 0) part[wv] = vsum;
  __syncthreads();
  if (threadIdx.x == 0)
    atomicAdd(scal, part[0] + part[1] + part[2] + part[3]);
}

// L3 bn_apply writes DIRECTLY into flat (fused flatten) + ssq into scal[1+b].
__global__ void bn_apply_flat_kernel(const float* __restrict__ y, const float* __restrict__ mean,
                                     const float* __restrict__ beta, const float* __restrict__ gamma,
                                     const float* __restrict__ scal_in, float* __restrict__ scal,
                                     float* __restrict__ flat, int P, int C){
  __shared__ float smean[260];
  __shared__ float sbeta[260];
  for (int i = threadIdx.x; i < C; i += blockDim.x){ smean[i] = mean[i]; sbeta[i] = beta[i]; }
  __syncthreads();
  int wv = threadIdx.x >> 6, lane = threadIdx.x & 63;
  int p = blockIdx.x*4 + wv;
  if (p >= P) return;
  const float* yp = y + (size_t)p * C;
  float yvv[5], ms[5], bs[5], nom[5], uc[5], u2[5];
  #pragma unroll
  for (int j = 0; j < 5; ++j){
    int c = lane + 64*j;
    yvv[j] = (c < C) ? yp[c] : 0.f;
    ms[j] = (c < C) ? smean[c] : 0.f;
    bs[j] = (c < C) ? sbeta[c] : 0.f;
  }
  float m0 = smean[0], b0 = sbeta[0];
  float d1 = 0.f;
  #pragma unroll
  for (int j = 0; j < 5; ++j){
    int c = lane + 64*j;
    float prd = yvv[j]*ms[j];
    d1 += (c == 0) ? -prd : prd;
  }
  float xy = wredf(d1);
  float dist = acoshf(fmaxf(-xy, 1.f + 1e-7f));
  float d2 = 0.f;
  #pragma unroll
  for (int j = 0; j < 5; ++j){
    nom[j] = yvv[j] + xy*ms[j];
    int c = lane + 64*j;
    float prd = nom[j]*nom[j];
    d2 += (c == 0) ? -prd : prd;
  }
  float den = sqrtf(fmaxf(wredf(d2), 1e-8f));
  float sc = dist / den;
  float u0 = __shfl(nom[0], 0, 64) * sc;
  float corr = -u0 / (1.f + m0);
  float var = scal_in[0] / (float)P;
  float g = gamma[0] / (var + 1e-5f);
  #pragma unroll
  for (int j = 0; j < 5; ++j){
    int c = lane + 64*j;
    uc[j] = (nom[j]*sc + corr*(ms[j] + ((c == 0) ? 1.f : 0.f))) * g;
  }
  float d3 = 0.f;
  #pragma unroll
  for (int j = 0; j < 5; ++j){
    int c = lane + 64*j;
    float prd = uc[j]*bs[j];
    d3 += (c == 0) ? -prd : prd;
  }
  float cb = wredf(d3) / (1.f + b0);
  float d4 = 0.f;
  #pragma unroll
  for (int j = 0; j < 5; ++j){
    int c = lane + 64*j;
    u2[j] = uc[j] + cb*(bs[j] + ((c == 0) ? 1.f : 0.f));
    float prd = u2[j]*u2[j];
    d4 += (c == 0) ? -prd : prd;
  }
  float nu = sqrtf(fmaxf(wredf(d4), 1e-8f));
  float ch = coshf(nu), shn = sinhf(nu) / nu;
  float ssum = 0.f;
  int b = p >> 8, n = p & 255;                 // N = 256 points per batch
  float* hp = flat + (size_t)b*65537 + 1 + (size_t)n*256;
  #pragma unroll
  for (int j = 0; j < 5; ++j){
    int c = lane + 64*j;
    if (c > 0 && c < C){
      float r = ch*sbeta[c] + shn*u2[j];
      r = fmaxf(r, 0.f);
      hp[c-1] = r;
      ssum += r*r;
    }
  }
  ssum = wredf(ssum);
  if (lane == 0) atomicAdd(&scal[1 + b], ssum);
}

__global__ void flat_time_kernel(float* __restrict__ flat, const float* __restrict__ scal){
  int b = threadIdx.x;
  if (b < 32) flat[(size_t)b*65537] = sqrtf(scal[1 + b] + 1.f);
}

// ---------------- h repack: flat (32,65537) fp32 -> (32,65536) bf16 ---------
__global__ void hconv_kernel(const float* __restrict__ flat, unsigned short* __restrict__ hbf){
  size_t base = ((size_t)blockIdx.x*256 + threadIdx.x) * 8;   // 2097152 total
  int b = (int)(base >> 16);
  int k = (int)(base & 65535);
  const float* src = flat + (size_t)b*65537 + k;
  union { unsigned short u[8]; uint4 q; } pk;
  #pragma unroll
  for (int j = 0; j < 8; ++j) pk.u[j] = f2bf(src[j]);
  *(uint4*)&hbf[base] = pk.q;
}

// ---------------- head GEMM v9: double-buffered LDS, ONE barrier/subchunk ---
// Per iteration: issue next global loads -> MFMA on buf[cur] (hides latency)
// -> convert+write buf[cur^1] -> single barrier. Write target != MFMA source;
// end-of-iteration barrier bounds cross-wave skew, so one barrier suffices.
__global__ __launch_bounds__(256) void fgemm_mfma_kernel(const float* __restrict__ wm,
    const float* __restrict__ wv, const unsigned short* __restrict__ hbf,
    float* __restrict__ mvacc){
  __shared__ __align__(16) unsigned short A_lds[2][64][136];
  __shared__ __align__(16) unsigned short B_lds[2][32][136];
  int tid = threadIdx.x;
  int wave = tid >> 6, lane = tid & 63;
  int kc = blockIdx.x * 512;
  int ob = blockIdx.y * 64;
  int row = lane & 15, kb = lane >> 4;
  int rA0 = tid >> 3, sA0 = tid & 7;            // rows 0..31
  int rA1 = rA0 + 32;                           // rows 32..63
  int o0 = ob + rA0, o1 = ob + rA1;
  const float* pA0 = ((o0 < 512) ? wm + (size_t)(o0 + 1)*65537
                                 : wv + (size_t)(o0 - 511)*65537) + kc + sA0*16;
  const float* pA1 = ((o1 < 512) ? wm + (size_t)(o1 + 1)*65537
                                 : wv + (size_t)(o1 - 511)*65537) + kc + sA0*16;
  const unsigned short* pB = hbf + (size_t)rA0*65536 + kc + sA0*16;

  float ra0[16], ra1[16];
  uint4 rb0, rb1;
  #pragma unroll
  for (int j = 0; j < 16; ++j){ ra0[j] = pA0[j]; ra1[j] = pA1[j]; }
  rb0 = *(const uint4*)&pB[0];
  rb1 = *(const uint4*)&pB[8];
  {
    union { unsigned short u[16]; uint4 q[2]; } k0, k1;
    #pragma unroll
    for (int j = 0; j < 16; ++j){ k0.u[j] = f2bf(ra0[j]); k1.u[j] = f2bf(ra1[j]); }
    *(uint4*)&A_lds[0][rA0][sA0*16]     = k0.q[0];
    *(uint4*)&A_lds[0][rA0][sA0*16 + 8] = k0.q[1];
    *(uint4*)&A_lds[0][rA1][sA0*16]     = k1.q[0];
    *(uint4*)&A_lds[0][rA1][sA0*16 + 8] = k1.q[1];
    *(uint4*)&B_lds[0][rA0][sA0*16]     = rb0;
    *(uint4*)&B_lds[0][rA0][sA0*16 + 8] = rb1;
  }
  __syncthreads();

  f32x4 zero = {0.f, 0.f, 0.f, 0.f};
  f32x4 acc[2] = {zero, zero};
  int m0 = wave*16;
  for (int sc = 0; sc < 4; ++sc){
    int cur = sc & 1;
    if (sc < 3){                       // issue next-subchunk loads (in flight)
      int off = (sc + 1)*128;
      #pragma unroll
      for (int j = 0; j < 16; ++j){ ra0[j] = pA0[off + j]; ra1[j] = pA1[off + j]; }
      rb0 = *(const uint4*)&pB[off];
      rb1 = *(const uint4*)&pB[off + 8];
    }
    #pragma unroll
    for (int ks = 0; ks < 4; ++ks){
      bf16x8 af = *(const bf16x8*)&A_lds[cur][m0 + row][ks*32 + kb*8];
      bf16x8 b0 = *(const bf16x8*)&B_lds[cur][row][ks*32 + kb*8];
      bf16x8 b1 = *(const bf16x8*)&B_lds[cur][16 + row][ks*32 + kb*8];
      acc[0] = __builtin_amdgcn_mfma_f32_16x16x32_bf16(af, b0, acc[0], 0, 0, 0);
      acc[1] = __builtin_amdgcn_mfma_f32_16x16x32_bf16(af, b1, acc[1], 0, 0, 0);
    }
    if (sc < 3){                       // convert+write NEXT buffer (no conflict)
      union { unsigned short u[16]; uint4 q[2]; } k0, k1;
      #pragma unroll
      for (int j = 0; j < 16; ++j){ k0.u[j] = f2bf(ra0[j]); k1.u[j] = f2bf(ra1[j]); }
      int nxt = cur ^ 1;
      *(uint4*)&A_lds[nxt][rA0][sA0*16]     = k0.q[0];
      *(uint4*)&A_lds[nxt][rA0][sA0*16 + 8] = k0.q[1];
      *(uint4*)&A_lds[nxt][rA1][sA0*16]     = k1.q[0];
      *(uint4*)&A_lds[nxt][rA1][sA0*16 + 8] = k1.q[1];
      *(uint4*)&B_lds[nxt][rA0][sA0*16]     = rb0;
      *(uint4*)&B_lds[nxt][rA0][sA0*16 + 8] = rb1;
    }
    __syncthreads();
  }
  #pragma unroll
  for (int nf = 0; nf < 2; ++nf){
    int b = nf*16 + row;
    #pragma unroll
    for (int r = 0; r < 4; ++r){
      int m = m0 + kb*4 + r;
      atomicAdd(&mvacc[(size_t)(ob + m)*32 + b], acc[nf][r]);
    }
  }
}

// ---------------- finalize: bias, k=65536 tail term, time, softplus ---------
__global__ void finalize_kernel(const float* __restrict__ mvacc, const float* __restrict__ bm,
                                const float* __restrict__ bv,
                                const float* __restrict__ wtail,
                                const float* __restrict__ flat, float* __restrict__ out){
  __shared__ float s[256];
  int b = blockIdx.x, tid = threadIdx.x;
  float hl = flat[(size_t)b*65537 + 65536];
  float m0 = mvacc[tid*32 + b] + bm[tid + 1] + wtail[tid] * hl;
  float m1 = mvacc[(tid + 256)*32 + b] + bm[tid + 257] + wtail[tid + 256] * hl;
  s[tid] = m0*m0 + m1*m1; __syncthreads();
  for (int st = 128; st; st >>= 1){ if (tid < st) s[tid] += s[tid+st]; __syncthreads(); }
  float t = sqrtf(s[0] + 1.f);
  float* om = out + (size_t)b*513;
  om[1 + tid] = m0;
  om[1 + tid + 256] = m1;
  if (tid == 0) om[0] = t;
  float v0 = mvacc[(512 + tid)*32 + b] + bv[tid + 1] + wtail[512 + tid] * hl;
  float v1 = mvacc[(512 + tid + 256)*32 + b] + bv[tid + 257] + wtail[768 + tid] * hl;
  float sp0 = fmaxf(v0, 0.f) + log1pf(expf(-fabsf(v0)));
  float sp1 = fmaxf(v1, 0.f) + log1pf(expf(-fabsf(v1)));
  float* ov = out + 32*513 + (size_t)b*512;
  ov[tid] = fmaxf(sp0, 1e-5f);
  ov[tid + 256] = fmaxf(sp1, 1e-5f);
}

extern "C" void kernel_launch(void* const* d_in, const int* in_sizes, int n_in,
                              void* d_out, int out_size, void* d_ws, size_t ws_size,
                              hipStream_t stream){
  const float* x  = (const float*)d_in[0];
  const float* cw[4] = {(const float*)d_in[1], (const float*)d_in[5], (const float*)d_in[9],  (const float*)d_in[13]};
  const float* cb[4] = {(const float*)d_in[2], (const float*)d_in[6], (const float*)d_in[10], (const float*)d_in[14]};
  const float* bb[4] = {(const float*)d_in[3], (const float*)d_in[7], (const float*)d_in[11], (const float*)d_in[15]};
  const float* bg[4] = {(const float*)d_in[4], (const float*)d_in[8], (const float*)d_in[12], (const float*)d_in[16]};
  const float* wm = (const float*)d_in[17];
  const float* bm = (const float*)d_in[18];
  const float* wv = (const float*)d_in[19];
  const float* bv = (const float*)d_in[20];
  float* ws = (float*)d_ws;

  // workspace (float offsets)
  float* Y = ws;                                          // <= 17.31M fp32 (or ushort view)
  unsigned short* Yh = (unsigned short*)ws;
  unsigned short* h0bf = (unsigned short*)(ws + 17500000);// 8.39M ush
  unsigned short* Sp   = (unsigned short*)(ws + 22000000);// <= 16.78M ush
  unsigned short* Tc   = (unsigned short*)(ws + 30500000);// <= 0.53M ush
  float* flatp = ws + 36500000;                           // 2.10M fp32
  unsigned short* hbf  = (unsigned short*)(ws + 39000000);// 2.1M ush
  float* red   = ws + 40500000;                           // 32*257
  float* meanp = ws + 40610000;
  float* scal  = ws + 40611000;
  float* mvacc = ws + 40620000;                           // 32768
  float* wtail = ws + 40660000;                           // 1024
  unsigned short* cwb0 = (unsigned short*)(ws + 40700000);
  unsigned short* cwb1 = (unsigned short*)(ws + 40710000);
  unsigned short* cwb2 = (unsigned short*)(ws + 40730000);
  unsigned short* cwb3 = (unsigned short*)(ws + 40780000);

  setup_kernel<<<1681, 256, 0, stream>>>(cw[0], cw[1], cw[2], cw[3], wm, wv,
                                         cwb0, cwb1, cwb2, cwb3, wtail, mvacc, red);

  h0_kernel<<<8192, 256, 0, stream>>>(x, h0bf);

  const int HoA[4]   = {128, 64, 32, 16};
  const int CoutA[4] = {33, 65, 129, 257};
  const int BPBA[4]  = {64, 32, 16, 8};

  for (int i = 0; i < 4; ++i){
    int Ho = HoA[i], Cout = CoutA[i], BPB = BPBA[i];
    int N = Ho * Ho;
    int P = 32 * N;
    switch (i){
      case 0:
        conv0_mfma_kernel<<<dim3(256,32), 256, 0, stream>>>(h0bf, cwb0, cw[0], cb[0], Yh, red);
        break;
      case 1:
        conv2_mfma_kernel<32,65,9,1,true,true><<<dim3(64,32,1), 256, 0, stream>>>(Sp, Tc, cwb1, cw[1], cb[1], (void*)Yh, red, 128, 64);
        break;
      case 2:
        conv2_mfma_kernel<64,129,18,1,false,false><<<dim3(16,32,2), 256, 0, stream>>>(Sp, Tc, cwb2, cw[2], cb[2], (void*)Y, red, 64, 32);
        break;
      case 3:
        hipMemsetAsync(Y, 0, (size_t)P*Cout*sizeof(float), stream);
        conv2_mfma_kernel<128,257,9,4,false,false><<<dim3(4,32,16), 256, 0, stream>>>(Sp, Tc, cwb3, cw[3], cb[3], (void*)Y, red, 32, 16);
        break;
    }
    if (i >= 2){
      switch (i){
        case 2:
          time_tile_kernel<129,64><<<P/64, 256, 0, stream>>>(Y);
          rsum_coal_kernel<129><<<dim3(BPB,32), 256, 0, stream>>>(Y, red, N, BPB);
          break;
        case 3:
          time_tile_kernel<257,32><<<P/32, 256, 0, stream>>>(Y);
          rsum_coal_kernel<257><<<dim3(BPB,32), 256, 0, stream>>>(Y, red, N, BPB);
          break;
      }
    }
    stats_kernel<<<1, 256, 0, stream>>>(red, meanp, scal, N, Cout);
    int pb = P / 256;
    int vb = min(pb, 2048);
    switch (i){
      case 0:
        bn_var_t_kernel<33,true><<<vb, 256, 0, stream>>>((const void*)Yh, meanp, scal, P);
        bn_apply_sp_kernel<33,true><<<pb, 256, 0, stream>>>((const void*)Yh, meanp, bb[i], bg[i], scal, Sp, Tc, P);
        break;
      case 1:
        bn_var_t_kernel<65,true><<<vb, 256, 0, stream>>>((const void*)Yh, meanp, scal, P);
        bn_apply_sp_kernel<65,true><<<pb, 256, 0, stream>>>((const void*)Yh, meanp, bb[i], bg[i], scal, Sp, Tc, P);
        break;
      case 2:
        bn_var_t_kernel<129,false><<<vb, 256, 0, stream>>>((const void*)Y, meanp, scal, P);
        bn_apply_sp_kernel<129,false><<<pb, 256, 0, stream>>>((const void*)Y, meanp, bb[i], bg[i], scal, Sp, Tc, P);
        break;
      case 3:
        bn_var_kernel<<<min((P + 3)/4, 2048), 256, 0, stream>>>(Y, meanp, scal, P, Cout);
        bn_apply_flat_kernel<<<(P + 3)/4, 256, 0, stream>>>(Y, meanp, bb[i], bg[i], scal, scal, flatp, P, Cout);
        break;
    }
  }

  flat_time_kernel<<<1, 64, 0, stream>>>(flatp, scal);
  hconv_kernel<<<1024, 256, 0, stream>>>(flatp, hbf);
  fgemm_mfma_kernel<<<dim3(128, 16), 256, 0, stream>>>(wm, wv, hbf, mvacc);
  finalize_kernel<<<32, 256, 0, stream>>>(mvacc, bm, bv, wtail, flatp, (float*)d_out);
}

// Round 21
// 542.868 us; speedup vs baseline: 1.0118x; 1.0118x over previous
//
#include <hip/hip_runtime.h>
#include <math.h>

#define DEV __device__ __forceinline__

typedef float f32x4 __attribute__((ext_vector_type(4)));
typedef __bf16 bf16x8 __attribute__((ext_vector_type(8)));

DEV unsigned short f2bf(float f){
  unsigned int u = __float_as_uint(f);
  u = (u + 0x7FFFu + ((u >> 16) & 1u)) >> 16;   // RNE
  return (unsigned short)u;
}
DEV float bf2f(unsigned short s){
  return __uint_as_float(((unsigned int)s) << 16);
}

DEV float wredf(float v){
  v += __shfl_xor(v, 32, 64);
  v += __shfl_xor(v, 16, 64);
  v += __shfl_xor(v, 8, 64);
  v += __shfl_xor(v, 4, 64);
  v += __shfl_xor(v, 2, 64);
  v += __shfl_xor(v, 1, 64);
  return v;
}

// ---------------- h0: (B,3,256,256) -> (B,256,256,4) bf16 with time ---------
__global__ void h0_kernel(const float* __restrict__ x, unsigned short* __restrict__ h0){
  int idx = blockIdx.x*256 + threadIdx.x;            // < 32*65536
  int b = idx >> 16, p = idx & 65535;
  const float* xb = x + (size_t)b*3*65536;
  float v0 = xb[p], v1 = xb[65536 + p], v2 = xb[131072 + p];
  float t = sqrtf(v0*v0 + v1*v1 + v2*v2 + 1.f);
  ushort4 o;
  o.x = f2bf(t); o.y = f2bf(v0); o.z = f2bf(v1); o.w = f2bf(v2);
  *(ushort4*)&h0[(size_t)idx*4] = o;
}

// ---------------- fused setup: conv-W repacks + wtail + zero mvacc/red ------
__global__ void setup_kernel(const float* __restrict__ cw0, const float* __restrict__ cw1,
                             const float* __restrict__ cw2, const float* __restrict__ cw3,
                             const float* __restrict__ wm, const float* __restrict__ wv,
                             unsigned short* __restrict__ cwb0, unsigned short* __restrict__ cwb1,
                             unsigned short* __restrict__ cwb2, unsigned short* __restrict__ cwb3,
                             float* __restrict__ wtail, float* __restrict__ mvacc,
                             float* __restrict__ red){
  int idx = blockIdx.x*256 + threadIdx.x;
  if (idx < 1024){
    int n = idx >> 5, kk = idx & 31;
    unsigned short v = 0;
    if (kk < 27){ int kp = kk/3, c = kk - kp*3; v = f2bf(cw0[(size_t)(n+1)*28 + 1 + c*9 + kp]); }
    cwb0[idx] = v;
    return;
  }
  idx -= 1024;
  if (idx < 18432){
    int n = idx / 288, kk = idx - n*288;
    int kp = kk / 32, c = kk - kp*32;
    cwb1[idx] = f2bf(cw1[(size_t)(n+1)*289 + 1 + c*9 + kp]);
    return;
  }
  idx -= 18432;
  if (idx < 73728){
    int n = idx / 576, kk = idx - n*576;
    int kp = kk / 64, c = kk - kp*64;
    cwb2[idx] = f2bf(cw2[(size_t)(n+1)*577 + 1 + c*9 + kp]);
    return;
  }
  idx -= 73728;
  if (idx < 294912){
    int n = idx / 1152, kk = idx - n*1152;
    int kp = kk / 128, c = kk - kp*128;
    cwb3[idx] = f2bf(cw3[(size_t)(n+1)*1153 + 1 + c*9 + kp]);
    return;
  }
  idx -= 294912;
  if (idx < 1024){
    wtail[idx] = (idx < 512) ? wm[(size_t)(idx + 1)*65537 + 65536]
                             : wv[(size_t)(idx - 511)*65537 + 65536];
    return;
  }
  idx -= 1024;
  if (idx < 32768){ mvacc[idx] = 0.f; return; }
  idx -= 32768;
  if (idx < 8224) red[idx] = 0.f;
}

// ---------------- conv layer 0 + fused time & channel sums (bf16 Y) --------
__global__ __launch_bounds__(256) void conv0_mfma_kernel(
    const unsigned short* __restrict__ h0bf, const unsigned short* __restrict__ wrp0,
    const float* __restrict__ Wm, const float* __restrict__ bias,
    unsigned short* __restrict__ y, float* __restrict__ red){
  __shared__ __align__(16) unsigned short A_lds[64][40];
  __shared__ __align__(16) unsigned short B_lds[32][40];
  __shared__ float Tsq[64][9];
  __shared__ float tA[64];
  __shared__ float bins[33];
  int tid = threadIdx.x;
  int tile = blockIdx.x, b = blockIdx.y;
  int oy0 = (tile >> 4) * 8, ox0 = (tile & 15) * 8;
  for (int i = tid; i < 320; i += 256){
    uint4 z = {0,0,0,0};
    *(uint4*)&A_lds[i/5][(i%5)*8] = z;
  }
  if (tid < 128)
    *(uint4*)&B_lds[tid>>2][(tid&3)*8] = *(const uint4*)&wrp0[(size_t)(tid>>2)*32 + (tid&3)*8];
  if (tid < 33) bins[tid] = 0.f;
  __syncthreads();
  for (int i = tid; i < 576; i += 256){
    int m = i/9, kp = i - (i/9)*9;
    int py = oy0 + (m >> 3), px = ox0 + (m & 7);
    int iy = py*2 + kp/3 - 1, ix = px*2 + kp%3 - 1;
    ushort4 v = {0x3F80, 0, 0, 0};     // OOB: t clamps to 1, space 0
    if ((unsigned)iy < 256u && (unsigned)ix < 256u)
      v = *(const ushort4*)&h0bf[((size_t)(b*256 + iy)*256 + ix)*4];
    A_lds[m][kp*3 + 0] = v.y;
    A_lds[m][kp*3 + 1] = v.z;
    A_lds[m][kp*3 + 2] = v.w;
    float tv = fmaxf(bf2f(v.x), 1.f);
    Tsq[m][kp] = tv*tv;
  }
  __syncthreads();
  if (tid < 64){
    float s = 0.f;
    #pragma unroll
    for (int kp = 0; kp < 9; ++kp) s += Tsq[tid][kp];
    tA[tid] = sqrtf(fmaxf(s - 8.f, 0.f));
  }
  int wave = tid >> 6, lane = tid & 63;
  int row = lane & 15, kb = lane >> 4;
  int m0 = wave * 16;
  f32x4 zero = {0.f,0.f,0.f,0.f};
  f32x4 acc0 = zero, acc1 = zero;
  bf16x8 af = *(const bf16x8*)&A_lds[m0 + row][kb*8];
  bf16x8 b0 = *(const bf16x8*)&B_lds[row][kb*8];
  bf16x8 b1 = *(const bf16x8*)&B_lds[16 + row][kb*8];
  acc0 = __builtin_amdgcn_mfma_f32_16x16x32_bf16(af, b0, acc0, 0, 0, 0);
  acc1 = __builtin_amdgcn_mfma_f32_16x16x32_bf16(af, b1, acc1, 0, 0, 0);
  __syncthreads();   // tA ready
  int o0 = row + 1, o1 = 17 + row;
  float bv0 = bias[o0], w00 = Wm[(size_t)o0*28];
  float bv1 = bias[o1], w01 = Wm[(size_t)o1*28];
  float v0[4], v1[4];
  #pragma unroll
  for (int r = 0; r < 4; ++r){
    int m = m0 + kb*4 + r;
    v0[r] = acc0[r] + bv0 + tA[m]*w00;
    v1[r] = acc1[r] + bv1 + tA[m]*w01;
    int py = oy0 + (m >> 3), px = ox0 + (m & 7);
    size_t pb_ = ((size_t)(b*128 + py)*128 + px)*33;
    y[pb_ + o0] = f2bf(v0[r]);
    y[pb_ + o1] = f2bf(v1[r]);
  }
  float sq[4];
  #pragma unroll
  for (int r = 0; r < 4; ++r) sq[r] = v0[r]*v0[r] + v1[r]*v1[r];
  #pragma unroll
  for (int msk = 1; msk <= 8; msk <<= 1)
    #pragma unroll
    for (int r = 0; r < 4; ++r) sq[r] += __shfl_xor(sq[r], msk, 64);
  float tvs = 0.f;
  #pragma unroll
  for (int r = 0; r < 4; ++r){
    float tv = sqrtf(sq[r] + 1.f);
    tvs += tv;
    if (row == 0){
      int m = m0 + kb*4 + r;
      int py = oy0 + (m >> 3), px = ox0 + (m & 7);
      y[((size_t)(b*128 + py)*128 + px)*33] = f2bf(tv);
    }
  }
  float cs0 = v0[0] + v0[1] + v0[2] + v0[3];
  float cs1 = v1[0] + v1[1] + v1[2] + v1[3];
  cs0 += __shfl_xor(cs0, 16, 64); cs0 += __shfl_xor(cs0, 32, 64);
  cs1 += __shfl_xor(cs1, 16, 64); cs1 += __shfl_xor(cs1, 32, 64);
  tvs += __shfl_xor(tvs, 16, 64); tvs += __shfl_xor(tvs, 32, 64);
  if (kb == 0){
    atomicAdd(&bins[o0], cs0);
    atomicAdd(&bins[o1], cs1);
    if (row == 0) atomicAdd(&bins[0], tvs);
  }
  __syncthreads();
  if (tid < 33) atomicAdd(&red[(size_t)b*33 + tid], bins[tid]);
}

// ---------------- conv layers 1-3: split Sp/T, repacked W, optional fusion --
template<int CS, int COUT, int KPC, int NSPLIT, bool FUSE, bool YBF>
__global__ __launch_bounds__(256) void conv2_mfma_kernel(
    const unsigned short* __restrict__ sp_in, const unsigned short* __restrict__ t_in,
    const unsigned short* __restrict__ wrp, const float* __restrict__ Wm,
    const float* __restrict__ bias, void* __restrict__ yv_,
    float* __restrict__ red, int Hin, int Ho){
  constexpr int KROW = 9*CS;
  __shared__ __align__(16) unsigned short A_lds[64][40];
  __shared__ __align__(16) unsigned short B_lds[64][40];
  __shared__ float tA[64];
  __shared__ float ssqS[FUSE ? 64 : 1];
  __shared__ float binsS[FUSE ? COUT : 1];
  float* yf = (float*)yv_;
  unsigned short* yh = (unsigned short*)yv_;
  int tid = threadIdx.x;
  int wave = tid >> 6, lane = tid & 63;
  int tilesX = Ho >> 3;
  int tile = blockIdx.x, b = blockIdx.y;
  int zt = blockIdx.z / NSPLIT, sp = blockIdx.z % NSPLIT;
  int zbase = zt * 64;
  int oy0 = (tile / tilesX) * 8, ox0 = (tile % tilesX) * 8;
  int m0 = (wave >> 1) * 32, n0 = (wave & 1) * 32;
  int row = lane & 15, kb = lane >> 4;
  if (FUSE){
    if (tid < 64) ssqS[tid] = 0.f;
    for (int i = tid; i < COUT; i += 256) binsS[i] = 0.f;
  }
  if (sp == 0 && tid < 64){
    int m = tid;
    int py = oy0 + (m >> 3), px = ox0 + (m & 7);
    float s = 0.f;
    #pragma unroll
    for (int kp = 0; kp < 9; ++kp){
      int iy = py*2 + kp/3 - 1, ix = px*2 + kp%3 - 1;
      float tv = 1.f;
      if ((unsigned)iy < (unsigned)Hin && (unsigned)ix < (unsigned)Hin)
        tv = fmaxf(bf2f(t_in[(size_t)(b*Hin + iy)*Hin + ix]), 1.f);
      s = fmaf(tv, tv, s);
    }
    tA[m] = sqrtf(fmaxf(s - 8.f, 0.f));
  }
  f32x4 zero = {0.f,0.f,0.f,0.f};
  f32x4 acc[2][2] = {{zero,zero},{zero,zero}};
  int ar = tid >> 2, aseg = tid & 3;
  int apy = oy0 + (ar >> 3), apx = ox0 + (ar & 7);
  for (int ch = sp*KPC; ch < sp*KPC + KPC; ++ch){
    int kglob = ch * 32;
    int kp = kglob / CS, c0 = kglob % CS;
    int iy = apy*2 + kp/3 - 1, ix = apx*2 + kp%3 - 1;
    uint4 va = {0,0,0,0};
    if ((unsigned)iy < (unsigned)Hin && (unsigned)ix < (unsigned)Hin)
      va = *(const uint4*)&sp_in[((size_t)(b*Hin + iy)*Hin + ix)*CS + c0 + aseg*8];
    uint4 vb = *(const uint4*)&wrp[(size_t)(zbase + ar)*KROW + kglob + aseg*8];
    __syncthreads();                       // prev chunk reads done
    *(uint4*)&A_lds[ar][aseg*8] = va;
    *(uint4*)&B_lds[ar][aseg*8] = vb;
    __syncthreads();
    bf16x8 af0 = *(const bf16x8*)&A_lds[m0 + row][kb*8];
    bf16x8 af1 = *(const bf16x8*)&A_lds[m0 + 16 + row][kb*8];
    bf16x8 bf0 = *(const bf16x8*)&B_lds[n0 + row][kb*8];
    bf16x8 bf1 = *(const bf16x8*)&B_lds[n0 + 16 + row][kb*8];
    acc[0][0] = __builtin_amdgcn_mfma_f32_16x16x32_bf16(af0, bf0, acc[0][0], 0, 0, 0);
    acc[0][1] = __builtin_amdgcn_mfma_f32_16x16x32_bf16(af0, bf1, acc[0][1], 0, 0, 0);
    acc[1][0] = __builtin_amdgcn_mfma_f32_16x16x32_bf16(af1, bf0, acc[1][0], 0, 0, 0);
    acc[1][1] = __builtin_amdgcn_mfma_f32_16x16x32_bf16(af1, bf1, acc[1][1], 0, 0, 0);
  }
  __syncthreads();
  float vv[2][2][4];
  #pragma unroll
  for (int mi = 0; mi < 2; ++mi)
    #pragma unroll
    for (int ni = 0; ni < 2; ++ni){
      int col = n0 + 16*ni + row;
      int o = zbase + 1 + col;
      float bv = 0.f, w0 = 0.f;
      if (sp == 0){ bv = bias[o]; w0 = Wm[(size_t)o*(KROW + 1)]; }
      #pragma unroll
      for (int r = 0; r < 4; ++r){
        int m = m0 + 16*mi + kb*4 + r;
        int py = oy0 + (m >> 3), px = ox0 + (m & 7);
        size_t idx = ((size_t)(b*Ho + py)*Ho + px)*COUT + o;
        float val = acc[mi][ni][r];
        if (sp == 0) val += bv + tA[m]*w0;
        vv[mi][ni][r] = val;
        if (YBF)              yh[idx] = f2bf(val);
        else if (NSPLIT > 1)  atomicAdd(&yf[idx], val);
        else                  yf[idx] = val;
      }
    }
  if (FUSE){
    float sq[2][4];
    #pragma unroll
    for (int mi = 0; mi < 2; ++mi)
      #pragma unroll
      for (int r = 0; r < 4; ++r)
        sq[mi][r] = vv[mi][0][r]*vv[mi][0][r] + vv[mi][1][r]*vv[mi][1][r];
    #pragma unroll
    for (int msk = 1; msk <= 8; msk <<= 1)
      #pragma unroll
      for (int mi = 0; mi < 2; ++mi)
        #pragma unroll
        for (int r = 0; r < 4; ++r) sq[mi][r] += __shfl_xor(sq[mi][r], msk, 64);
    if (row == 0){
      #pragma unroll
      for (int mi = 0; mi < 2; ++mi)
        #pragma unroll
        for (int r = 0; r < 4; ++r)
          atomicAdd(&ssqS[m0 + 16*mi + kb*4 + r], sq[mi][r]);
    }
    float cs[2];
    #pragma unroll
    for (int ni = 0; ni < 2; ++ni){
      cs[ni] = 0.f;
      #pragma unroll
      for (int mi = 0; mi < 2; ++mi)
        #pragma unroll
        for (int r = 0; r < 4; ++r) cs[ni] += vv[mi][ni][r];
      cs[ni] += __shfl_xor(cs[ni], 16, 64);
      cs[ni] += __shfl_xor(cs[ni], 32, 64);
    }
    if (kb == 0){
      atomicAdd(&binsS[1 + n0 + row], cs[0]);
      atomicAdd(&binsS[1 + n0 + 16 + row], cs[1]);
    }
    __syncthreads();
    if (tid < 64){
      float tv = sqrtf(ssqS[tid] + 1.f);
      int py = oy0 + (tid >> 3), px = ox0 + (tid & 7);
      size_t idx = ((size_t)(b*Ho + py)*Ho + px)*COUT;
      if (YBF) yh[idx] = f2bf(tv);
      else     yf[idx] = tv;
      atomicAdd(&binsS[0], tv);
    }
    __syncthreads();
    for (int i = tid; i < COUT; i += 256)
      atomicAdd(&red[(size_t)b*COUT + i], binsS[i]);
  }
}

// ---------------- time channel via LDS tile (L2/L3 only, fp32) --------------
template<int C, int TP>
__global__ __launch_bounds__(256) void time_tile_kernel(float* __restrict__ y){
  constexpr int TPR = 256 / TP;
  __shared__ float tile[TP*C];
  int tid = threadIdx.x;
  size_t base = (size_t)blockIdx.x * TP * C;
  for (int i = tid; i < TP*C; i += 256) tile[i] = y[base + i];
  __syncthreads();
  int r = tid / TPR, seg = tid % TPR;
  float ss = 0.f;
  for (int c = 1 + seg; c < C; c += TPR){ float v = tile[r*C + c]; ss = fmaf(v, v, ss); }
  #pragma unroll
  for (int m = TPR/2; m >= 1; m >>= 1) ss += __shfl_xor(ss, m, 64);
  if (seg == 0) y[base + (size_t)r*C] = sqrtf(ss + 1.f);
}

// ---------------- coalesced channel sums (L2/L3 only, fp32) -----------------
template<int C>
__global__ __launch_bounds__(256) void rsum_coal_kernel(const float* __restrict__ y,
    float* __restrict__ red, int N, int BPB){
  constexpr int S = (4096 / C) * C;
  __shared__ float bins[C];
  int tid = threadIdx.x;
  for (int i = tid; i < C; i += 256) bins[i] = 0.f;
  int b = blockIdx.y, blk = blockIdx.x;
  size_t per = (size_t)(N / BPB) * C;
  const float* yb = y + (size_t)b*N*C + (size_t)blk*per;
  float a[16];
  #pragma unroll
  for (int k = 0; k < 16; ++k) a[k] = 0.f;
  for (size_t off = 0; off < per; off += S){
    #pragma unroll
    for (int k = 0; k < 16; ++k){
      int e = k*256 + tid;
      if (e < S && off + e < per) a[k] += yb[off + e];
    }
  }
  __syncthreads();            // bins zeroed
  #pragma unroll
  for (int k = 0; k < 16; ++k){
    int e = k*256 + tid;
    if (e < S) atomicAdd(&bins[e % C], a[k]);
  }
  __syncthreads();
  for (int i = tid; i < C; i += 256) atomicAdd(&red[(size_t)b*C + i], bins[i]);
}

// ---------------- fused stats: per-b centroid + centroid-of-centroids -------
__global__ __launch_bounds__(256) void stats_kernel(float* __restrict__ red,
    float* __restrict__ mean, float* __restrict__ scal, int N, int C){
  __shared__ float cent[8224];      // 32 x C (C<=257)
  __shared__ float s[256];
  int tid = threadIdx.x;
  int wave = tid >> 6, lane = tid & 63;
  for (int j = 0; j < 8; ++j){
    int b = wave*8 + j;
    float va[5]; float d = 0.f;
    #pragma unroll
    for (int k = 0; k < 5; ++k){
      int c = lane + 64*k;
      float v = 0.f;
      if (c < C){ v = red[(size_t)b*C + c] / (float)N; red[(size_t)b*C + c] = 0.f; }
      va[k] = v;
      float pr = v*v;
      d += (c == 0) ? -pr : pr;
    }
    float den = sqrtf(fmaxf(fabsf(wredf(d)), 1e-8f));
    #pragma unroll
    for (int k = 0; k < 5; ++k){
      int c = lane + 64*k;
      if (c < C) cent[b*C + c] = va[k] / den;
    }
  }
  __syncthreads();
  float va = 0.f, vb = 0.f;
  if (tid < C){
    #pragma unroll 4
    for (int b = 0; b < 32; ++b) va += cent[b*C + tid];
    va *= 0.03125f;
  }
  if (tid + 256 < C){
    #pragma unroll 4
    for (int b = 0; b < 32; ++b) vb += cent[b*C + tid + 256];
    vb *= 0.03125f;
  }
  float pr = ((tid == 0) ? -va*va : va*va) + vb*vb;
  s[tid] = pr; __syncthreads();
  for (int st = 128; st; st >>= 1){ if (tid < st) s[tid] += s[tid+st]; __syncthreads(); }
  float den2 = sqrtf(fmaxf(fabsf(s[0]), 1e-8f));
  if (tid < C) mean[tid] = va / den2;
  if (tid + 256 < C) mean[tid + 256] = vb / den2;
  if (tid < 40) scal[tid] = 0.f;
}

// ---------------- Frechet variance, thread-per-point (YBF: bf16 input) ------
template<int C, bool YBF>
__global__ __launch_bounds__(256) void bn_var_t_kernel(const void* __restrict__ yv_,
    const float* __restrict__ mean, float* __restrict__ scal, int P){
  __shared__ float sm[C];
  __shared__ float part[4];
  const float* yf = (const float*)yv_;
  const unsigned short* yh = (const unsigned short*)yv_;
  for (int i = threadIdx.x; i < C; i += 256) sm[i] = mean[i];
  __syncthreads();
  float acc = 0.f;
  int stride = gridDim.x * 256;
  for (int p = blockIdx.x*256 + threadIdx.x; p < P; p += stride){
    float a[C];
    float d1 = 0.f;
    #pragma unroll
    for (int c = 0; c < C; ++c){
      a[c] = YBF ? bf2f(yh[(size_t)p*C + c]) : yf[(size_t)p*C + c];
      float pr = a[c]*sm[c];
      d1 += (c == 0) ? -pr : pr;
    }
    float xy = d1;
    float dist = acoshf(fmaxf(-xy, 1.f + 1e-7f));
    float d2 = 0.f;
    #pragma unroll
    for (int c = 0; c < C; ++c){
      a[c] = fmaf(xy, sm[c], a[c]);
      float pr = a[c]*a[c];
      d2 += (c == 0) ? -pr : pr;
    }
    float den = sqrtf(fmaxf(d2, 1e-8f));
    float sc = dist / den;
    float corr = -(a[0]*sc) / (1.f + sm[0]);
    float ns = 0.f;
    #pragma unroll
    for (int c = 0; c < C; ++c){
      float uc = fmaf(corr, sm[c] + ((c == 0) ? 1.f : 0.f), a[c]*sc);
      ns = fmaf(uc, uc, ns);
    }
    acc += sqrtf(ns);
  }
  acc = wredf(acc);
  if ((threadIdx.x & 63) == 0) part[threadIdx.x >> 6] = acc;
  __syncthreads();
  if (threadIdx.x == 0)
    atomicAdd(scal, part[0] + part[1] + part[2] + part[3]);
}

// ---------------- BN apply, thread-per-point, split bf16 out (L0-2) ---------
template<int C, bool YBF>
__global__ __launch_bounds__(256) void bn_apply_sp_kernel(const void* __restrict__ yv_,
    const float* __restrict__ mean, const float* __restrict__ beta,
    const float* __restrict__ gamma, const float* __restrict__ scal,
    unsigned short* __restrict__ sp_out, unsigned short* __restrict__ t_out, int P){
  __shared__ float sm[C];
  __shared__ float sb[C];
  const float* yf = (const float*)yv_;
  const unsigned short* yh = (const unsigned short*)yv_;
  for (int i = threadIdx.x; i < C; i += 256){ sm[i] = mean[i]; sb[i] = beta[i]; }
  __syncthreads();
  int p = blockIdx.x*256 + threadIdx.x;
  if (p >= P) return;
  float a[C];
  float d1 = 0.f;
  #pragma unroll
  for (int c = 0; c < C; ++c){
    a[c] = YBF ? bf2f(yh[(size_t)p*C + c]) : yf[(size_t)p*C + c];
    float pr = a[c]*sm[c];
    d1 += (c == 0) ? -pr : pr;
  }
  float xy = d1;
  float dist = acoshf(fmaxf(-xy, 1.f + 1e-7f));
  float d2 = 0.f;
  #pragma unroll
  for (int c = 0; c < C; ++c){
    a[c] = fmaf(xy, sm[c], a[c]);
    float pr = a[c]*a[c];
    d2 += (c == 0) ? -pr : pr;
  }
  float den = sqrtf(fmaxf(d2, 1e-8f));
  float sc = dist / den;
  float corr = -(a[0]*sc) / (1.f + sm[0]);
  float var = scal[0] / (float)P;
  float g = gamma[0] / (var + 1e-5f);
  #pragma unroll
  for (int c = 0; c < C; ++c)
    a[c] = fmaf(corr, sm[c] + ((c == 0) ? 1.f : 0.f), a[c]*sc) * g;
  float d3 = 0.f;
  #pragma unroll
  for (int c = 0; c < C; ++c){
    float pr = a[c]*sb[c];
    d3 += (c == 0) ? -pr : pr;
  }
  float cb = d3 / (1.f + sb[0]);
  float d4 = 0.f;
  #pragma unroll
  for (int c = 0; c < C; ++c){
    a[c] = fmaf(cb, sb[c] + ((c == 0) ? 1.f : 0.f), a[c]);
    float pr = a[c]*a[c];
    d4 += (c == 0) ? -pr : pr;
  }
  float nu = sqrtf(fmaxf(d4, 1e-8f));
  float ch = coshf(nu), shn = sinhf(nu) / nu;
  unsigned short* hp = sp_out + (size_t)p * (C - 1);
  float ssum = 0.f;
  #pragma unroll
  for (int c = 1; c < C; ++c){
    float r = fmaxf(fmaf(ch, sb[c], shn*a[c]), 0.f);
    hp[c-1] = f2bf(r);
    ssum = fmaf(r, r, ssum);
  }
  t_out[p] = f2bf(sqrtf(ssum + 1.f));
}

// ---------------- L3 (C=257) wave-per-point fallbacks (fp32) ----------------
__global__ void bn_var_kernel(const float* __restrict__ y, const float* __restrict__ mean,
                              float* __restrict__ scal, int P, int C){
  __shared__ float smean[260];
  __shared__ float part[4];
  for (int i = threadIdx.x; i < C; i += blockDim.x) smean[i] = mean[i];
  __syncthreads();
  int wv = threadIdx.x >> 6, lane = threadIdx.x & 63;
  int nwaves = gridDim.x * 4;
  float m0 = smean[0];
  float ms[5];
  #pragma unroll
  for (int j = 0; j < 5; ++j){
    int c = lane + 64*j;
    ms[j] = (c < C) ? smean[c] : 0.f;
  }
  float vsum = 0.f;
  for (int p = blockIdx.x*4 + wv; p < P; p += nwaves){
    const float* yp = y + (size_t)p * C;
    float yvv[5], nom[5];
    #pragma unroll
    for (int j = 0; j < 5; ++j){
      int c = lane + 64*j;
      yvv[j] = (c < C) ? yp[c] : 0.f;
    }
    float d1 = 0.f;
    #pragma unroll
    for (int j = 0; j < 5; ++j){
      int c = lane + 64*j;
      float prd = yvv[j]*ms[j];
      d1 += (c == 0) ? -prd : prd;
    }
    float xy = wredf(d1);
    float dist = acoshf(fmaxf(-xy, 1.f + 1e-7f));
    float d2 = 0.f;
    #pragma unroll
    for (int j = 0; j < 5; ++j){
      int c = lane + 64*j;
      nom[j] = yvv[j] + xy*ms[j];
      float prd = nom[j]*nom[j];
      d2 += (c == 0) ? -prd : prd;
    }
    float den = sqrtf(fmaxf(wredf(d2), 1e-8f));
    float sc = dist / den;
    float u0 = __shfl(nom[0], 0, 64) * sc;
    float corr = -u0 / (1.f + m0);
    float nsum = 0.f;
    #pragma unroll
    for (int j = 0; j < 5; ++j){
      int c = lane + 64*j;
      float uc = nom[j]*sc + corr*(ms[j] + ((c == 0) ? 1.f : 0.f));
      nsum += uc*uc;
    }
    nsum = wredf(nsum);
    vsum += sqrtf(nsum);
  }
  if (lane == 0) part[wv] = vsum;
  __syncthreads();
  if (threadIdx.x == 0)
    atomicAdd(scal, part[0] + part[1] + part[2] + part[3]);
}

// L3 bn_apply writes DIRECTLY into flat (fused flatten) + ssq into scal[1+b].
__global__ void bn_apply_flat_kernel(const float* __restrict__ y, const float* __restrict__ mean,
                                     const float* __restrict__ beta, const float* __restrict__ gamma,
                                     const float* __restrict__ scal_in, float* __restrict__ scal,
                                     float* __restrict__ flat, int P, int C){
  __shared__ float smean[260];
  __shared__ float sbeta[260];
  for (int i = threadIdx.x; i < C; i += blockDim.x){ smean[i] = mean[i]; sbeta[i] = beta[i]; }
  __syncthreads();
  int wv = threadIdx.x >> 6, lane = threadIdx.x & 63;
  int p = blockIdx.x*4 + wv;
  if (p >= P) return;
  const float* yp = y + (size_t)p * C;
  float yvv[5], ms[5], bs[5], nom[5], uc[5], u2[5];
  #pragma unroll
  for (int j = 0; j < 5; ++j){
    int c = lane + 64*j;
    yvv[j] = (c < C) ? yp[c] : 0.f;
    ms[j] = (c < C) ? smean[c] : 0.f;
    bs[j] = (c < C) ? sbeta[c] : 0.f;
  }
  float m0 = smean[0], b0 = sbeta[0];
  float d1 = 0.f;
  #pragma unroll
  for (int j = 0; j < 5; ++j){
    int c = lane + 64*j;
    float prd = yvv[j]*ms[j];
    d1 += (c == 0) ? -prd : prd;
  }
  float xy = wredf(d1);
  float dist = acoshf(fmaxf(-xy, 1.f + 1e-7f));
  float d2 = 0.f;
  #pragma unroll
  for (int j = 0; j < 5; ++j){
    nom[j] = yvv[j] + xy*ms[j];
    int c = lane + 64*j;
    float prd = nom[j]*nom[j];
    d2 += (c == 0) ? -prd : prd;
  }
  float den = sqrtf(fmaxf(wredf(d2), 1e-8f));
  float sc = dist / den;
  float u0 = __shfl(nom[0], 0, 64) * sc;
  float corr = -u0 / (1.f + m0);
  float var = scal_in[0] / (float)P;
  float g = gamma[0] / (var + 1e-5f);
  #pragma unroll
  for (int j = 0; j < 5; ++j){
    int c = lane + 64*j;
    uc[j] = (nom[j]*sc + corr*(ms[j] + ((c == 0) ? 1.f : 0.f))) * g;
  }
  float d3 = 0.f;
  #pragma unroll
  for (int j = 0; j < 5; ++j){
    int c = lane + 64*j;
    float prd = uc[j]*bs[j];
    d3 += (c == 0) ? -prd : prd;
  }
  float cb = wredf(d3) / (1.f + b0);
  float d4 = 0.f;
  #pragma unroll
  for (int j = 0; j < 5; ++j){
    int c = lane + 64*j;
    u2[j] = uc[j] + cb*(bs[j] + ((c == 0) ? 1.f : 0.f));
    float prd = u2[j]*u2[j];
    d4 += (c == 0) ? -prd : prd;
  }
  float nu = sqrtf(fmaxf(wredf(d4), 1e-8f));
  float ch = coshf(nu), shn = sinhf(nu) / nu;
  float ssum = 0.f;
  int b = p >> 8, n = p & 255;                 // N = 256 points per batch
  float* hp = flat + (size_t)b*65537 + 1 + (size_t)n*256;
  #pragma unroll
  for (int j = 0; j < 5; ++j){
    int c = lane + 64*j;
    if (c > 0 && c < C){
      float r = ch*sbeta[c] + shn*u2[j];
      r = fmaxf(r, 0.f);
      hp[c-1] = r;
      ssum += r*r;
    }
  }
  ssum = wredf(ssum);
  if (lane == 0) atomicAdd(&scal[1 + b], ssum);
}

__global__ void flat_time_kernel(float* __restrict__ flat, const float* __restrict__ scal){
  int b = threadIdx.x;
  if (b < 32) flat[(size_t)b*65537] = sqrtf(scal[1 + b] + 1.f);
}

// ---------------- h repack: flat (32,65537) fp32 -> (32,65536) bf16 ---------
__global__ void hconv_kernel(const float* __restrict__ flat, unsigned short* __restrict__ hbf){
  size_t base = ((size_t)blockIdx.x*256 + threadIdx.x) * 8;   // 2097152 total
  int b = (int)(base >> 16);
  int k = (int)(base & 65535);
  const float* src = flat + (size_t)b*65537 + k;
  union { unsigned short u[8]; uint4 q; } pk;
  #pragma unroll
  for (int j = 0; j < 8; ++j) pk.u[j] = f2bf(src[j]);
  *(uint4*)&hbf[base] = pk.q;
}

// ---------------- head GEMM v8: fused W convert, bf16 h (pre-packed) --------
__global__ __launch_bounds__(256) void fgemm_mfma_kernel(const float* __restrict__ wm,
    const float* __restrict__ wv, const unsigned short* __restrict__ hbf,
    float* __restrict__ mvacc){
  __shared__ __align__(16) unsigned short A_lds[64][136];
  __shared__ __align__(16) unsigned short B_lds[32][136];
  int tid = threadIdx.x;
  int wave = tid >> 6, lane = tid & 63;
  int kc = blockIdx.x * 512;
  int ob = blockIdx.y * 64;
  int row = lane & 15, kb = lane >> 4;
  int rA0 = tid >> 3, sA0 = tid & 7;            // rows 0..31
  int rA1 = rA0 + 32;                           // rows 32..63
  int o0 = ob + rA0, o1 = ob + rA1;
  const float* pA0 = ((o0 < 512) ? wm + (size_t)(o0 + 1)*65537
                                 : wv + (size_t)(o0 - 511)*65537) + kc + sA0*16;
  const float* pA1 = ((o1 < 512) ? wm + (size_t)(o1 + 1)*65537
                                 : wv + (size_t)(o1 - 511)*65537) + kc + sA0*16;
  const unsigned short* pB = hbf + (size_t)rA0*65536 + kc + sA0*16;

  float ra0[16], ra1[16];
  uint4 rb0, rb1;
  #pragma unroll
  for (int j = 0; j < 16; ++j){ ra0[j] = pA0[j]; ra1[j] = pA1[j]; }
  rb0 = *(const uint4*)&pB[0];
  rb1 = *(const uint4*)&pB[8];

  f32x4 zero = {0.f, 0.f, 0.f, 0.f};
  f32x4 acc[2] = {zero, zero};
  for (int sc = 0; sc < 4; ++sc){
    union { unsigned short u[16]; uint4 q[2]; } k0, k1;
    #pragma unroll
    for (int j = 0; j < 16; ++j){ k0.u[j] = f2bf(ra0[j]); k1.u[j] = f2bf(ra1[j]); }
    *(uint4*)&A_lds[rA0][sA0*16]     = k0.q[0];
    *(uint4*)&A_lds[rA0][sA0*16 + 8] = k0.q[1];
    *(uint4*)&A_lds[rA1][sA0*16]     = k1.q[0];
    *(uint4*)&A_lds[rA1][sA0*16 + 8] = k1.q[1];
    *(uint4*)&B_lds[rA0][sA0*16]     = rb0;
    *(uint4*)&B_lds[rA0][sA0*16 + 8] = rb1;
    __syncthreads();
    if (sc < 3){                       // prefetch next subchunk under MFMA
      int off = (sc + 1)*128;
      #pragma unroll
      for (int j = 0; j < 16; ++j){ ra0[j] = pA0[off + j]; ra1[j] = pA1[off + j]; }
      rb0 = *(const uint4*)&pB[off];
      rb1 = *(const uint4*)&pB[off + 8];
    }
    int m0 = wave*16;
    #pragma unroll
    for (int ks = 0; ks < 4; ++ks){
      bf16x8 af = *(const bf16x8*)&A_lds[m0 + row][ks*32 + kb*8];
      bf16x8 b0 = *(const bf16x8*)&B_lds[row][ks*32 + kb*8];
      bf16x8 b1 = *(const bf16x8*)&B_lds[16 + row][ks*32 + kb*8];
      acc[0] = __builtin_amdgcn_mfma_f32_16x16x32_bf16(af, b0, acc[0], 0, 0, 0);
      acc[1] = __builtin_amdgcn_mfma_f32_16x16x32_bf16(af, b1, acc[1], 0, 0, 0);
    }
    __syncthreads();
  }
  int m0 = wave*16;
  #pragma unroll
  for (int nf = 0; nf < 2; ++nf){
    int b = nf*16 + row;
    #pragma unroll
    for (int r = 0; r < 4; ++r){
      int m = m0 + kb*4 + r;
      atomicAdd(&mvacc[(size_t)(ob + m)*32 + b], acc[nf][r]);
    }
  }
}

// ---------------- finalize: bias, k=65536 tail term, time, softplus ---------
__global__ void finalize_kernel(const float* __restrict__ mvacc, const float* __restrict__ bm,
                                const float* __restrict__ bv,
                                const float* __restrict__ wtail,
                                const float* __restrict__ flat, float* __restrict__ out){
  __shared__ float s[256];
  int b = blockIdx.x, tid = threadIdx.x;
  float hl = flat[(size_t)b*65537 + 65536];
  float m0 = mvacc[tid*32 + b] + bm[tid + 1] + wtail[tid] * hl;
  float m1 = mvacc[(tid + 256)*32 + b] + bm[tid + 257] + wtail[tid + 256] * hl;
  s[tid] = m0*m0 + m1*m1; __syncthreads();
  for (int st = 128; st; st >>= 1){ if (tid < st) s[tid] += s[tid+st]; __syncthreads(); }
  float t = sqrtf(s[0] + 1.f);
  float* om = out + (size_t)b*513;
  om[1 + tid] = m0;
  om[1 + tid + 256] = m1;
  if (tid == 0) om[0] = t;
  float v0 = mvacc[(512 + tid)*32 + b] + bv[tid + 1] + wtail[512 + tid] * hl;
  float v1 = mvacc[(512 + tid + 256)*32 + b] + bv[tid + 257] + wtail[768 + tid] * hl;
  float sp0 = fmaxf(v0, 0.f) + log1pf(expf(-fabsf(v0)));
  float sp1 = fmaxf(v1, 0.f) + log1pf(expf(-fabsf(v1)));
  float* ov = out + 32*513 + (size_t)b*512;
  ov[tid] = fmaxf(sp0, 1e-5f);
  ov[tid + 256] = fmaxf(sp1, 1e-5f);
}

extern "C" void kernel_launch(void* const* d_in, const int* in_sizes, int n_in,
                              void* d_out, int out_size, void* d_ws, size_t ws_size,
                              hipStream_t stream){
  const float* x  = (const float*)d_in[0];
  const float* cw[4] = {(const float*)d_in[1], (const float*)d_in[5], (const float*)d_in[9],  (const float*)d_in[13]};
  const float* cb[4] = {(const float*)d_in[2], (const float*)d_in[6], (const float*)d_in[10], (const float*)d_in[14]};
  const float* bb[4] = {(const float*)d_in[3], (const float*)d_in[7], (const float*)d_in[11], (const float*)d_in[15]};
  const float* bg[4] = {(const float*)d_in[4], (const float*)d_in[8], (const float*)d_in[12], (const float*)d_in[16]};
  const float* wm = (const float*)d_in[17];
  const float* bm = (const float*)d_in[18];
  const float* wv = (const float*)d_in[19];
  const float* bv = (const float*)d_in[20];
  float* ws = (float*)d_ws;

  // workspace (float offsets)
  float* Y = ws;                                          // <= 17.31M fp32 (or ushort view)
  unsigned short* Yh = (unsigned short*)ws;
  unsigned short* h0bf = (unsigned short*)(ws + 17500000);// 8.39M ush
  unsigned short* Sp   = (unsigned short*)(ws + 22000000);// <= 16.78M ush
  unsigned short* Tc   = (unsigned short*)(ws + 30500000);// <= 0.53M ush
  float* flatp = ws + 36500000;                           // 2.10M fp32
  unsigned short* hbf  = (unsigned short*)(ws + 39000000);// 2.1M ush
  float* red   = ws + 40500000;                           // 32*257
  float* meanp = ws + 40610000;
  float* scal  = ws + 40611000;
  float* mvacc = ws + 40620000;                           // 32768
  float* wtail = ws + 40660000;                           // 1024
  unsigned short* cwb0 = (unsigned short*)(ws + 40700000);
  unsigned short* cwb1 = (unsigned short*)(ws + 40710000);
  unsigned short* cwb2 = (unsigned short*)(ws + 40730000);
  unsigned short* cwb3 = (unsigned short*)(ws + 40780000);

  setup_kernel<<<1681, 256, 0, stream>>>(cw[0], cw[1], cw[2], cw[3], wm, wv,
                                         cwb0, cwb1, cwb2, cwb3, wtail, mvacc, red);

  h0_kernel<<<8192, 256, 0, stream>>>(x, h0bf);

  const int HoA[4]   = {128, 64, 32, 16};
  const int CoutA[4] = {33, 65, 129, 257};
  const int BPBA[4]  = {64, 32, 16, 8};

  for (int i = 0; i < 4; ++i){
    int Ho = HoA[i], Cout = CoutA[i], BPB = BPBA[i];
    int N = Ho * Ho;
    int P = 32 * N;
    switch (i){
      case 0:
        conv0_mfma_kernel<<<dim3(256,32), 256, 0, stream>>>(h0bf, cwb0, cw[0], cb[0], Yh, red);
        break;
      case 1:
        conv2_mfma_kernel<32,65,9,1,true,true><<<dim3(64,32,1), 256, 0, stream>>>(Sp, Tc, cwb1, cw[1], cb[1], (void*)Yh, red, 128, 64);
        break;
      case 2:
        conv2_mfma_kernel<64,129,18,1,false,false><<<dim3(16,32,2), 256, 0, stream>>>(Sp, Tc, cwb2, cw[2], cb[2], (void*)Y, red, 64, 32);
        break;
      case 3:
        hipMemsetAsync(Y, 0, (size_t)P*Cout*sizeof(float), stream);
        conv2_mfma_kernel<128,257,9,4,false,false><<<dim3(4,32,16), 256, 0, stream>>>(Sp, Tc, cwb3, cw[3], cb[3], (void*)Y, red, 32, 16);
        break;
    }
    if (i >= 2){
      switch (i){
        case 2:
          time_tile_kernel<129,64><<<P/64, 256, 0, stream>>>(Y);
          rsum_coal_kernel<129><<<dim3(BPB,32), 256, 0, stream>>>(Y, red, N, BPB);
          break;
        case 3:
          time_tile_kernel<257,32><<<P/32, 256, 0, stream>>>(Y);
          rsum_coal_kernel<257><<<dim3(BPB,32), 256, 0, stream>>>(Y, red, N, BPB);
          break;
      }
    }
    stats_kernel<<<1, 256, 0, stream>>>(red, meanp, scal, N, Cout);
    int pb = P / 256;
    int vb = min(pb, 2048);
    switch (i){
      case 0:
        bn_var_t_kernel<33,true><<<vb, 256, 0, stream>>>((const void*)Yh, meanp, scal, P);
        bn_apply_sp_kernel<33,true><<<pb, 256, 0, stream>>>((const void*)Yh, meanp, bb[i], bg[i], scal, Sp, Tc, P);
        break;
      case 1:
        bn_var_t_kernel<65,true><<<vb, 256, 0, stream>>>((const void*)Yh, meanp, scal, P);
        bn_apply_sp_kernel<65,true><<<pb, 256, 0, stream>>>((const void*)Yh, meanp, bb[i], bg[i], scal, Sp, Tc, P);
        break;
      case 2:
        bn_var_t_kernel<129,false><<<vb, 256, 0, stream>>>((const void*)Y, meanp, scal, P);
        bn_apply_sp_kernel<129,false><<<pb, 256, 0, stream>>>((const void*)Y, meanp, bb[i], bg[i], scal, Sp, Tc, P);
        break;
      case 3:
        bn_var_kernel<<<min((P + 3)/4, 2048), 256, 0, stream>>>(Y, meanp, scal, P, Cout);
        bn_apply_flat_kernel<<<(P + 3)/4, 256, 0, stream>>>(Y, meanp, bb[i], bg[i], scal, scal, flatp, P, Cout);
        break;
    }
  }

  flat_time_kernel<<<1, 64, 0, stream>>>(flatp, scal);
  hconv_kernel<<<1024, 256, 0, stream>>>(flatp, hbf);
  fgemm_mfma_kernel<<<dim3(128, 16), 256, 0, stream>>>(wm, wv, hbf, mvacc);
  finalize_kernel<<<32, 256, 0, stream>>>(mvacc, bm, bv, wtail, flatp, (float*)d_out);
}